// Round 10
// baseline (81.689 us; speedup 1.0000x reference)
//
#include <hip/hip_runtime.h>
#include <math.h>

#define HH 512
#define WW 512
#define NPIX (16*HH*WW)
#define RAD 10
#define KS 21
#define TX 64
#define TY 32
// mega tile: output 64x32, staged 74x42; swizzled cols: phys = col + (col+5)/6, stride 87
#define SH 42
#define SW 74
#define SSTR 87

__device__ __forceinline__ int refl(int v, int n){ v = v < 0 ? -v : v; return v >= n ? 2*n - 2 - v : v; }
__device__ __forceinline__ float sigm(float x){ return 1.f/(1.f+expf(-x)); }

// P layout: [0]=alpha [1]=lam [2]=beta [3]=xi [4]=eta [5]=nu [6]=gamma [7]=omega
// [8..28]=gauss weights  [30]=saturation flag  [64+32*i]=per-image max slots
__global__ void k_params(const float* a_raw, const float* l_raw, const float* lsig,
                         const float* lbeta, const float* lxi, const float* e_raw,
                         const float* n_raw, const float* lgam, const float* o_raw,
                         float* P)
{
    if (threadIdx.x || blockIdx.x) return;
    float sigma = 0.5f + 4.5f*sigm(lsig[0]);
    float beta  = 1.f + 4.f*sigm(lbeta[0]);
    float xi    = 1.f + 4.f*sigm(lxi[0]);
    float eta   = sigm(e_raw[0]);
    P[0] = 0.6f + 1.4f*sigm(a_raw[0]);
    P[1] = 0.01f + 0.19f*sigm(l_raw[0]);
    P[2] = beta;
    P[3] = xi;
    P[4] = eta;
    P[5] = sigm(n_raw[0]);
    P[6] = 1.f + 3.f*sigm(lgam[0]);
    P[7] = sigm(o_raw[0]);
    float kk[KS], s = 0.f;
    for (int i = 0; i < KS; ++i){ float c = (float)(i-RAD); kk[i] = expf(-c*c/(2.f*sigma*sigma+1e-8f)); s += kk[i]; }
    float inv = 1.f/(s+1e-8f);
    for (int i = 0; i < KS; ++i) P[8+i] = kk[i]*inv;
    // phi saturates at 10 for ALL u in [0,1] iff beta^2*xi >= 100*(eta*g2max+1e-6), g2max=0.5.
    P[30] = (beta*beta*xi >= 100.f*(eta*0.5000002f + 1e-6f)) ? 1.f : 0.f;
    for (int i = 0; i < 16; ++i) P[64+32*i] = 0.f;
}

// 6 in-patch values (rows a/d)
#define ROW6(v, S, off) float v##0=(S)[(off)], v##1=(S)[(off)+1], v##2=(S)[(off)+2], \
                              v##3=(S)[(off)+3], v##4=(S)[(off)+4], v##5=(S)[(off)+5];
// 6 in-patch + W (-2) + E (+7) (rows b/c) -- swizzle holes make these static offsets
#define ROW8S(v, S, off) float v##m=(S)[(off)-2], v##0=(S)[(off)], v##1=(S)[(off)+1], v##2=(S)[(off)+2], \
                               v##3=(S)[(off)+3], v##4=(S)[(off)+4], v##5=(S)[(off)+5], v##6=(S)[(off)+7];

// Saturated-phi path: 5 iterations in LDS ping-pong with patch-hole swizzle
// (phys col = col + (col+5)/6 -> lane bank step 7, coprime w/ 32), static 6x2
// patch per thread, fw-edges + u0 in named scalar registers, fixed compute region.
__global__ __launch_bounds__(256, 5)
void k_mega(const float* __restrict__ img, const float* __restrict__ lfd,
            float* __restrict__ out_u, float* __restrict__ out_r,
            const float* __restrict__ P, float* Pmax)
{
    if (P[30] == 0.f) return;
    __shared__ float SA[SH*SSTR];
    __shared__ float SB[SH*SSTR];
    __shared__ float red[4];
    const int tid = threadIdx.x;
    const bool active = tid < 240;
    const int pid = active ? tid : 0;
    const int py = pid / 12;            // 0..19
    const int px = pid - 12*py;         // 0..11
    const int ox = blockIdx.x * TX, oy = blockIdx.y * TY;
    const int b = blockIdx.z;
    const float* ib = img + (b<<18);
    const float* lb = lfd + (b<<18);
    const float A = 1e-3f*P[0], lam = P[1], nu = P[5], gam = P[6], omg = P[7];
    const bool bord = (ox == 0) | (oy == 0) | (ox == WW - TX) | (oy == HH - TY);

    // stage u0 -> SA, fw -> SB (patch-hole swizzled columns)
    for (int i = tid; i < SW*SH; i += 256){
        int r = i / SW, c = i - r*SW;
        int gy = oy - 5 + r, gx = ox - 5 + c;
        if (bord){ gy = refl(gy, HH); gx = refl(gx, WW); }
        int gi = gy*WW + gx;
        int pc = c + (c + 5) / 6;
        SA[r*SSTR + pc] = ib[gi];
        SB[r*SSTR + pc] = fminf(fmaxf(1.f - omg*lb[gi], 0.f), 1.f);
    }
    __syncthreads();

    const int c0 = 1 + 6*px;            // logical first col (1..67)
    const int r0 = 1 + 2*py;            // rows r0, r0+1 (1..39)
    const int bi = r0*SSTR + 7*px + 2;  // phys base of (r0, c0)

    // hoist fw window + u0 into named scalars
    ROW6(fa, SB, bi-SSTR) ROW8S(fb, SB, bi) ROW8S(fc, SB, bi+SSTR) ROW6(fd, SB, bi+2*SSTR)
    float zb0=SA[bi],   zb1=SA[bi+1],   zb2=SA[bi+2],   zb3=SA[bi+3],   zb4=SA[bi+4],   zb5=SA[bi+5];
    float zc0=SA[bi+SSTR], zc1=SA[bi+SSTR+1], zc2=SA[bi+SSTR+2], zc3=SA[bi+SSTR+3], zc4=SA[bi+SSTR+4], zc5=SA[bi+SSTR+5];
    __syncthreads();    // all fw reads done before iter1 overwrites SB

    auto CF = [&](float cc, float cn, float cs, float cw, float ce,
                  float fn, float fs, float fww, float fe, float z) -> float {
        float gyv = (cs - cn)*0.5f, gxv = (ce - cw)*0.5f;
        float lap = (cn + cs) + (ce + cw) - 4.f*cc;
        float gm = sqrtf(fmaf(gxv, gxv, fmaf(gyv, gyv, 1e-8f)));
        float s = gm*fabsf(lap);
        float psi = sqrtf(fmaf(nu, s*s*s, gam));
        float dv = fn*(cn-cc) + fs*(cs-cc) + fe*(ce-cc) + fww*(cw-cc);
        float du = fmaf(A*psi, dv, -lam*(cc - z));
        return fminf(fmaxf(fmaf(0.1f, du, cc), 0.f), 1.f);
    };

#define CELLS \
    float nb0 = CF(ub0, ua0, uc0, ubm, ub1, fa0, fc0, fbm, fb1, zb0); \
    float nb1 = CF(ub1, ua1, uc1, ub0, ub2, fa1, fc1, fb0, fb2, zb1); \
    float nb2 = CF(ub2, ua2, uc2, ub1, ub3, fa2, fc2, fb1, fb3, zb2); \
    float nb3 = CF(ub3, ua3, uc3, ub2, ub4, fa3, fc3, fb2, fb4, zb3); \
    float nb4 = CF(ub4, ua4, uc4, ub3, ub5, fa4, fc4, fb3, fb5, zb4); \
    float nb5 = CF(ub5, ua5, uc5, ub4, ub6, fa5, fc5, fb4, fb6, zb5); \
    float nc0 = CF(uc0, ub0, ud0, ucm, uc1, fb0, fd0, fcm, fc1, zc0); \
    float nc1 = CF(uc1, ub1, ud1, uc0, uc2, fb1, fd1, fc0, fc2, zc1); \
    float nc2 = CF(uc2, ub2, ud2, uc1, uc3, fb2, fd2, fc1, fc3, zc2); \
    float nc3 = CF(uc3, ub3, ud3, uc2, uc4, fb3, fd3, fc2, fc4, zc3); \
    float nc4 = CF(uc4, ub4, ud4, uc3, uc5, fb4, fd4, fc3, fc5, zc4); \
    float nc5 = CF(uc5, ub5, ud5, uc4, uc6, fb5, fd5, fc4, fc6, zc5);

#define STEP(S, D) { \
    ROW6(ua, S, bi-SSTR) ROW8S(ub, S, bi) ROW8S(uc, S, bi+SSTR) ROW6(ud, S, bi+2*SSTR) \
    CELLS \
    if (active){ \
        D[bi]   = nb0; D[bi+1] = nb1; D[bi+2] = nb2; D[bi+3] = nb3; D[bi+4] = nb4; D[bi+5] = nb5; \
        D[bi+SSTR]   = nc0; D[bi+SSTR+1] = nc1; D[bi+SSTR+2] = nc2; \
        D[bi+SSTR+3] = nc3; D[bi+SSTR+4] = nc4; D[bi+SSTR+5] = nc5; \
    } \
    } __syncthreads();

    STEP(SA, SB)
    STEP(SB, SA)
    STEP(SA, SB)
    STEP(SB, SA)

    // final iteration: compute + store core (logical rows 5..36, cols 5..68)
    float mymax = 0.f;
    {
        ROW6(ua, SA, bi-SSTR) ROW8S(ub, SA, bi) ROW8S(uc, SA, bi+SSTR) ROW6(ud, SA, bi+2*SSTR)
        CELLS
        if (active && py >= 2 && py <= 17){
            float* ou  = out_u + (b<<18) + (oy + r0 - 5)*WW + (ox + c0 - 5);
            float* orr = out_r + (b<<18) + (oy + r0 - 5)*WW + (ox + c0 - 5);
#define EMIT(K, NB, NC, ZB, ZC) \
            if (c0 + K >= 5 && c0 + K <= 68){ \
                ou[K] = NB; ou[WW + K] = NC; \
                float vb = fabsf(ZB - NB), vc = fabsf(ZC - NC); \
                orr[K] = vb; orr[WW + K] = vc; \
                mymax = fmaxf(mymax, fmaxf(vb, vc)); \
            }
            EMIT(0, nb0, nc0, zb0, zc0)
            EMIT(1, nb1, nc1, zb1, zc1)
            EMIT(2, nb2, nc2, zb2, zc2)
            EMIT(3, nb3, nc3, zb3, zc3)
            EMIT(4, nb4, nc4, zb4, zc4)
            EMIT(5, nb5, nc5, zb5, zc5)
#undef EMIT
        }
    }
#undef STEP
#undef CELLS

#pragma unroll
    for (int off = 32; off; off >>= 1) mymax = fmaxf(mymax, __shfl_down(mymax, off));
    if ((tid & 63) == 0) red[tid >> 6] = mymax;
    __syncthreads();
    if (tid == 0){
        float m = fmaxf(fmaxf(red[0], red[1]), fmaxf(red[2], red[3]));
        atomicMax((unsigned int*)(Pmax + 32*b), __float_as_uint(m));
    }
}

// General-path fallback (fully-fused single iteration). Early-exits when saturated.
__global__ __launch_bounds__(256)
void k_iter(const float* __restrict__ src, const float* __restrict__ img,
            const float* __restrict__ lfd, float* __restrict__ dst,
            float* __restrict__ resid,
            const float* __restrict__ P, float* Pmax, int do_max)
{
    if (P[30] != 0.f) return;
    __shared__ __attribute__((aligned(16))) float sh[56][72];
    __shared__ float su[36][72];
    __shared__ float ut[34][72];
    __shared__ float red[4];
    float (*pt)[72] = sh;

    const int tid = threadIdx.x;
    const int x0 = blockIdx.x * TX;
    const int y0 = blockIdx.y * TY;
    const int b  = blockIdx.z;
    const float* sb = src + (b << 18);
    const float* ib = img + (b << 18);
    const float* lb = lfd + (b << 18);
    float* db = dst + (b << 18);

    float kw[KS];
#pragma unroll
    for (int j = 0; j < KS; ++j) kw[j] = P[8 + j];
    const float alpha = P[0], lam = P[1], beta = P[2], xi = P[3];
    const float eta = P[4], nu = P[5], gam = P[6], omg = P[7];

#pragma unroll
    for (int p = 0; p < 9; ++p) {
        int i = tid + p * 256;
        if (i < 34 * 66) {
            int r = i / 66, c = i - r * 66;
            ut[r][c] = sb[refl(y0 - 1 + r, HH) * WW + refl(x0 - 1 + c, WW)];
        }
    }
#pragma unroll
    for (int p = 0; p < 4; ++p) {
        int i = tid + p * 256;
        if (i < 56 * 17) {
            int hr = i / 17, g = i - hr * 17;
            const float* row = sb + refl(y0 - 12 + hr, HH) * WW;
            int gxs = x0 - 12 + 4 * g;
            float wv[24];
            if (gxs >= 0 && gxs + 23 < WW) {
                const float4* p4 = (const float4*)(row + gxs);
#pragma unroll
                for (int q = 0; q < 6; ++q) {
                    float4 v = p4[q];
                    wv[4*q] = v.x; wv[4*q+1] = v.y; wv[4*q+2] = v.z; wv[4*q+3] = v.w;
                }
            } else {
#pragma unroll
                for (int q = 0; q < 24; ++q) wv[q] = row[refl(gxs + q, WW)];
            }
            float a0 = 0.f, a1 = 0.f, a2 = 0.f, a3 = 0.f;
#pragma unroll
            for (int j = 0; j < KS; ++j) {
                a0 = fmaf(kw[j], wv[j],     a0);
                a1 = fmaf(kw[j], wv[j + 1], a1);
                a2 = fmaf(kw[j], wv[j + 2], a2);
                a3 = fmaf(kw[j], wv[j + 3], a3);
            }
            float4 o; o.x = a0; o.y = a1; o.z = a2; o.w = a3;
            *(float4*)&sh[hr][4 * g] = o;
        }
    }
    __syncthreads();
#pragma unroll
    for (int p = 0; p < 3; ++p) {
        int i = tid + p * 256;
        if (i < 9 * 68) {
            int rg = i / 68, c = i - rg * 68;
            int r0 = rg * 4;
            float a0 = 0.f, a1 = 0.f, a2 = 0.f, a3 = 0.f;
#pragma unroll
            for (int q = 0; q < 24; ++q) {
                float s = sh[r0 + q][c];
                if (q <= 20)           a0 = fmaf(kw[q],     s, a0);
                if (q >= 1 && q <= 21) a1 = fmaf(kw[q - 1], s, a1);
                if (q >= 2 && q <= 22) a2 = fmaf(kw[q - 2], s, a2);
                if (q >= 3)            a3 = fmaf(kw[q - 3], s, a3);
            }
            su[r0][c] = a0; su[r0+1][c] = a1; su[r0+2][c] = a2; su[r0+3][c] = a3;
        }
    }
    __syncthreads();
#pragma unroll
    for (int p = 0; p < 9; ++p) {
        int i = tid + p * 256;
        if (i < 34 * 66) {
            int r = i / 66, c = i - r * 66;
            float gys = (su[r + 2][c + 1] - su[r][c + 1]) * 0.5f;
            float gxs = (su[r + 1][c + 2] - su[r + 1][c]) * 0.5f;
            float g2 = fmaf(gxs, gxs, fmaf(gys, gys, 1e-8f));
            float ph = fminf(beta * sqrtf(xi / fmaf(eta, g2, 1e-6f)), 10.f);
            float lv = lb[refl(y0 - 1 + r, HH) * WW + refl(x0 - 1 + c, WW)];
            float fwv = fminf(fmaxf(1.f - omg * lv, 0.f), 1.f);
            pt[r][c] = ph * fwv;
        }
    }
    __syncthreads();
    const int c = tid & 63, r0 = tid >> 6;
    float mymax = 0.f;
#pragma unroll
    for (int p = 0; p < 8; ++p) {
        int r = r0 + p * 4;
        float uc = ut[r + 1][c + 1];
        float uN = ut[r][c + 1],     uS = ut[r + 2][c + 1];
        float uE = ut[r + 1][c + 2], uW = ut[r + 1][c];
        float gy = (uS - uN) * 0.5f, gx = (uE - uW) * 0.5f;
        float lap = uN + uS + uE + uW - 4.f * uc;
        float gm = sqrtf(fmaf(gx, gx, fmaf(gy, gy, 1e-8f)));
        float s = gm * fabsf(lap);
        float psi = 1e-4f * sqrtf(fmaf(nu, s * s * s, gam));
        float pN = pt[r][c + 1],     pS = pt[r + 2][c + 1];
        float pE = pt[r + 1][c + 2], pW = pt[r + 1][c];
        float dv = pN * (uN - uc) + pS * (uS - uc) + pE * (uE - uc) + pW * (uW - uc);
        int gidx = (y0 + r) * WW + x0 + c;
        float u0v = ib[gidx];
        float du = alpha * psi * dv - lam * (uc - u0v);
        float un = fminf(fmaxf(fmaf(0.1f, du, uc), 0.f), 1.f);
        db[gidx] = un;
        if (do_max){
            float v = fabsf(u0v - un);
            resid[(b<<18) + gidx] = v;
            mymax = fmaxf(mymax, v);
        }
    }
    if (do_max) {
#pragma unroll
        for (int off = 32; off; off >>= 1) mymax = fmaxf(mymax, __shfl_down(mymax, off));
        if ((tid & 63) == 0) red[tid >> 6] = mymax;
        __syncthreads();
        if (tid == 0) {
            float m = fmaxf(fmaxf(red[0], red[1]), fmaxf(red[2], red[3]));
            atomicMax((unsigned int*)(Pmax + 32 * b), __float_as_uint(m));
        }
    }
}

// in-place normalize of residual
__global__ void k_res2(float* __restrict__ r, const float* __restrict__ Pmax)
{
    int i = blockIdx.x * 256 + threadIdx.x;   // float4 index
    int b = i >> 16;
    float inv = 1.f / (Pmax[32 * b] + 1e-8f);
    float4 v = ((const float4*)r)[i];
    v.x *= inv; v.y *= inv; v.z *= inv; v.w *= inv;
    ((float4*)r)[i] = v;
}

extern "C" void kernel_launch(void* const* d_in, const int* in_sizes, int n_in,
                              void* d_out, int out_size, void* d_ws, size_t ws_size,
                              hipStream_t stream)
{
    const float* image = (const float*)d_in[0];
    const float* lfd   = (const float*)d_in[1];

    float* out_u = (float*)d_out;
    float* out_r = out_u + NPIX;

    float* uB = (float*)d_ws;           // NPIX floats (fallback ping-pong)
    float* P  = uB + NPIX;              // params + max slots

    k_params<<<1, 64, 0, stream>>>((const float*)d_in[2], (const float*)d_in[3],
                                   (const float*)d_in[4], (const float*)d_in[5],
                                   (const float*)d_in[6], (const float*)d_in[7],
                                   (const float*)d_in[8], (const float*)d_in[9],
                                   (const float*)d_in[10], P);

    float* Pmax = P + 64;

    // saturated-phi fast path (no-op if not saturated)
    dim3 grd(WW/TX, HH/TY, 16), blk(256);
    k_mega<<<grd, blk, 0, stream>>>(image, lfd, out_u, out_r, P, Pmax);

    // general fallback (no-op if saturated)
    float* bufs[2] = { out_u, uB };
    for (int it = 0; it < 5; ++it) {
        const float* src = (it == 0) ? image : bufs[(it + 1) & 1];
        float* dstp = bufs[it & 1];
        k_iter<<<grd, blk, 0, stream>>>(src, image, lfd, dstp, out_r, P, Pmax, it == 4 ? 1 : 0);
    }

    k_res2<<<NPIX/1024, 256, 0, stream>>>(out_r, Pmax);
}

// Round 11
// 75.855 us; speedup vs baseline: 1.0769x; 1.0769x over previous
//
#include <hip/hip_runtime.h>
#include <math.h>

#define HH 512
#define WW 512
#define NPIX (16*HH*WW)
#define RAD 10
#define KS 21
#define TX 64
#define TY 32
// mega tile: staged 42 rows x 74 logical cols; patch px (6 cols) at phys 7*px+2,
// row stride 90  =>  wave bank = 7*pid mod 32: every bank exactly 2 lanes (free).
#define SH 42
#define SW 74
#define SSTR 90

__device__ __forceinline__ int refl(int v, int n){ v = v < 0 ? -v : v; return v >= n ? 2*n - 2 - v : v; }
__device__ __forceinline__ float sigm(float x){ return 1.f/(1.f+expf(-x)); }

// P layout: [0]=alpha [1]=lam [2]=beta [3]=xi [4]=eta [5]=nu [6]=gamma [7]=omega
// [8..28]=gauss weights  [30]=saturation flag  [64+32*i]=per-image max slots
__global__ void k_params(const float* a_raw, const float* l_raw, const float* lsig,
                         const float* lbeta, const float* lxi, const float* e_raw,
                         const float* n_raw, const float* lgam, const float* o_raw,
                         float* P)
{
    if (threadIdx.x || blockIdx.x) return;
    float sigma = 0.5f + 4.5f*sigm(lsig[0]);
    float beta  = 1.f + 4.f*sigm(lbeta[0]);
    float xi    = 1.f + 4.f*sigm(lxi[0]);
    float eta   = sigm(e_raw[0]);
    P[0] = 0.6f + 1.4f*sigm(a_raw[0]);
    P[1] = 0.01f + 0.19f*sigm(l_raw[0]);
    P[2] = beta;
    P[3] = xi;
    P[4] = eta;
    P[5] = sigm(n_raw[0]);
    P[6] = 1.f + 3.f*sigm(lgam[0]);
    P[7] = sigm(o_raw[0]);
    float kk[KS], s = 0.f;
    for (int i = 0; i < KS; ++i){ float c = (float)(i-RAD); kk[i] = expf(-c*c/(2.f*sigma*sigma+1e-8f)); s += kk[i]; }
    float inv = 1.f/(s+1e-8f);
    for (int i = 0; i < KS; ++i) P[8+i] = kk[i]*inv;
    // phi saturates at 10 for ALL u in [0,1] iff beta^2*xi >= 100*(eta*g2max+1e-6), g2max=0.5.
    P[30] = (beta*beta*xi >= 100.f*(eta*0.5000002f + 1e-6f)) ? 1.f : 0.f;
    for (int i = 0; i < 16; ++i) P[64+32*i] = 0.f;
}

// 6 in-patch values
#define ROW6(v, S, off) float v##0=(S)[(off)], v##1=(S)[(off)+1], v##2=(S)[(off)+2], \
                              v##3=(S)[(off)+3], v##4=(S)[(off)+4], v##5=(S)[(off)+5];
// 6 in-patch + W (-2) + E (+7): holes make neighbors static offsets
#define ROW8S(v, S, off) float v##m=(S)[(off)-2], v##0=(S)[(off)], v##1=(S)[(off)+1], v##2=(S)[(off)+2], \
                               v##3=(S)[(off)+3], v##4=(S)[(off)+4], v##5=(S)[(off)+5], v##6=(S)[(off)+7];

// Saturated-phi path: 5 iterations; own 2x6 cell patch lives in REGISTERS across
// iterations; only the 16 halo values are read from LDS per iter (12 writes).
// fw window, per-cell fsum, u0 all hoisted to named scalars. Bank-perfect layout.
__global__ __launch_bounds__(256, 4)
void k_mega(const float* __restrict__ img, const float* __restrict__ lfd,
            float* __restrict__ out_u, float* __restrict__ out_r,
            const float* __restrict__ P, float* Pmax)
{
    if (P[30] == 0.f) return;
    __shared__ float SA[SH*SSTR];
    __shared__ float SB[SH*SSTR];
    __shared__ float red[4];
    const int tid = threadIdx.x;
    const bool active = tid < 240;
    const int py = tid / 12;            // 0..21 (>=20 inactive, stray reads harmless)
    const int px = tid - 12*py;         // 0..11
    const int ox = blockIdx.x * TX, oy = blockIdx.y * TY;
    const int b = blockIdx.z;
    const float* ib = img + (b<<18);
    const float* lb = lfd + (b<<18);
    const float A = 1e-3f*P[0], lam = P[1], nu = P[5], gam = P[6], omg = P[7];
    const float nuA = A*A*nu, gamA = A*A*gam;
    const bool bord = (ox == 0) | (oy == 0) | (ox == WW - TX) | (oy == HH - TY);

    // stage u0 -> SA, fw -> SB (patch-hole layout: c=0 -> 0, else c + (c-1)/6 + 1)
    for (int i = tid; i < SW*SH; i += 256){
        int r = i / SW, c = i - r*SW;
        int gy = oy - 5 + r, gx = ox - 5 + c;
        if (bord){ gy = refl(gy, HH); gx = refl(gx, WW); }
        int gi = gy*WW + gx;
        int pc = (c == 0) ? 0 : (c + (c-1)/6 + 1);
        SA[r*SSTR + pc] = ib[gi];
        SB[r*SSTR + pc] = fminf(fmaxf(1.f - omg*lb[gi], 0.f), 1.f);
    }
    __syncthreads();

    const int c0 = 1 + 6*px;            // logical first col (1..67)
    const int r0 = 1 + 2*py;            // rows r0, r0+1
    const int bi = r0*SSTR + 7*px + 2;  // phys base of (r0, c0)

    // hoist fw window, u0, initial u into named scalars
    ROW6(fa, SB, bi-SSTR) ROW8S(fb, SB, bi) ROW8S(fc, SB, bi+SSTR) ROW6(fd, SB, bi+2*SSTR)
    ROW6(zb, SA, bi) ROW6(zc, SA, bi+SSTR)
    __syncthreads();    // all SB (fw) reads done before iter1 overwrites SB

    // per-cell fsum = fN+fS+fW+fE (iteration-invariant)
    const float wb0 = fa0+fc0+fbm+fb1, wb1 = fa1+fc1+fb0+fb2, wb2 = fa2+fc2+fb1+fb3;
    const float wb3 = fa3+fc3+fb2+fb4, wb4 = fa4+fc4+fb3+fb5, wb5 = fa5+fc5+fb4+fb6;
    const float wc0 = fb0+fd0+fcm+fc1, wc1 = fb1+fd1+fc0+fc2, wc2 = fb2+fd2+fc1+fc3;
    const float wc3 = fb3+fd3+fc2+fc4, wc4 = fb4+fd4+fc3+fc5, wc5 = fb5+fd5+fc4+fc6;

    // own cells in registers
    float ub0=zb0, ub1=zb1, ub2=zb2, ub3=zb3, ub4=zb4, ub5=zb5;
    float uc0=zc0, uc1=zc1, uc2=zc2, uc3=zc3, uc4=zc4, uc5=zc5;

    auto CF = [&](float cc, float cn, float cs, float cw, float ce,
                  float fn, float fs, float fw_, float fe, float fsum, float z) -> float {
        float dy = cs - cn, dx = ce - cw;
        float g2 = fmaf(0.25f, fmaf(dy, dy, dx*dx), 1e-8f);
        float t1 = (cn + cs) + (ce + cw);
        float lap = fmaf(-4.f, cc, t1);
        float s = sqrtf(g2) * fabsf(lap);
        float psiA = sqrtf(fmaf(nuA, s*s*s, gamA));
        float dv = fmaf(fn, cn, fmaf(fs, cs, fmaf(fe, ce, fmaf(fw_, cw, -cc*fsum))));
        float du = fmaf(psiA, dv, -lam*(cc - z));
        return fminf(fmaxf(fmaf(0.1f, du, cc), 0.f), 1.f);
    };

#define READ_HALO(S) \
    ROW6(ua, S, bi-SSTR) ROW6(ud, S, bi+2*SSTR) \
    float ubm=(S)[bi-2], ub6=(S)[bi+7], ucm=(S)[bi+SSTR-2], uc6=(S)[bi+SSTR+7];

#define CELLS \
    float nb0 = CF(ub0, ua0, uc0, ubm, ub1, fa0, fc0, fbm, fb1, wb0, zb0); \
    float nb1 = CF(ub1, ua1, uc1, ub0, ub2, fa1, fc1, fb0, fb2, wb1, zb1); \
    float nb2 = CF(ub2, ua2, uc2, ub1, ub3, fa2, fc2, fb1, fb3, wb2, zb2); \
    float nb3 = CF(ub3, ua3, uc3, ub2, ub4, fa3, fc3, fb2, fb4, wb3, zb3); \
    float nb4 = CF(ub4, ua4, uc4, ub3, ub5, fa4, fc4, fb3, fb5, wb4, zb4); \
    float nb5 = CF(ub5, ua5, uc5, ub4, ub6, fa5, fc5, fb4, fb6, wb5, zb5); \
    float nc0 = CF(uc0, ub0, ud0, ucm, uc1, fb0, fd0, fcm, fc1, wc0, zc0); \
    float nc1 = CF(uc1, ub1, ud1, uc0, uc2, fb1, fd1, fc0, fc2, wc1, zc1); \
    float nc2 = CF(uc2, ub2, ud2, uc1, uc3, fb2, fd2, fc1, fc3, wc2, zc2); \
    float nc3 = CF(uc3, ub3, ud3, uc2, uc4, fb3, fd3, fc2, fc4, wc3, zc3); \
    float nc4 = CF(uc4, ub4, ud4, uc3, uc5, fb4, fd4, fc3, fc5, wc4, zc4); \
    float nc5 = CF(uc5, ub5, ud5, uc4, uc6, fb5, fd5, fc4, fc6, wc5, zc5);

#define STEP(S, D) { \
    READ_HALO(S) \
    CELLS \
    if (active){ \
        D[bi]   = nb0; D[bi+1] = nb1; D[bi+2] = nb2; D[bi+3] = nb3; D[bi+4] = nb4; D[bi+5] = nb5; \
        D[bi+SSTR]   = nc0; D[bi+SSTR+1] = nc1; D[bi+SSTR+2] = nc2; \
        D[bi+SSTR+3] = nc3; D[bi+SSTR+4] = nc4; D[bi+SSTR+5] = nc5; \
    } \
    ub0=nb0; ub1=nb1; ub2=nb2; ub3=nb3; ub4=nb4; ub5=nb5; \
    uc0=nc0; uc1=nc1; uc2=nc2; uc3=nc3; uc4=nc4; uc5=nc5; \
    } __syncthreads();

    STEP(SA, SB)
    STEP(SB, SA)
    STEP(SA, SB)
    STEP(SB, SA)

    // final iteration: compute + store core (logical rows 5..36, cols 5..68)
    float mymax = 0.f;
    {
        READ_HALO(SA)
        CELLS
        if (active && py >= 2 && py <= 17){
            float* ou  = out_u + (b<<18) + (oy + r0 - 5)*WW + (ox + c0 - 5);
            float* orr = out_r + (b<<18) + (oy + r0 - 5)*WW + (ox + c0 - 5);
#define EMIT(K, NB, NC, ZB, ZC) \
            if (c0 + K >= 5 && c0 + K <= 68){ \
                ou[K] = NB; ou[WW + K] = NC; \
                float vb = fabsf(ZB - NB), vc = fabsf(ZC - NC); \
                orr[K] = vb; orr[WW + K] = vc; \
                mymax = fmaxf(mymax, fmaxf(vb, vc)); \
            }
            EMIT(0, nb0, nc0, zb0, zc0)
            EMIT(1, nb1, nc1, zb1, zc1)
            EMIT(2, nb2, nc2, zb2, zc2)
            EMIT(3, nb3, nc3, zb3, zc3)
            EMIT(4, nb4, nc4, zb4, zc4)
            EMIT(5, nb5, nc5, zb5, zc5)
#undef EMIT
        }
    }
#undef STEP
#undef CELLS
#undef READ_HALO

#pragma unroll
    for (int off = 32; off; off >>= 1) mymax = fmaxf(mymax, __shfl_down(mymax, off));
    if ((tid & 63) == 0) red[tid >> 6] = mymax;
    __syncthreads();
    if (tid == 0){
        float m = fmaxf(fmaxf(red[0], red[1]), fmaxf(red[2], red[3]));
        atomicMax((unsigned int*)(Pmax + 32*b), __float_as_uint(m));
    }
}

// General-path fallback (fully-fused single iteration). Early-exits when saturated.
__global__ __launch_bounds__(256)
void k_iter(const float* __restrict__ src, const float* __restrict__ img,
            const float* __restrict__ lfd, float* __restrict__ dst,
            float* __restrict__ resid,
            const float* __restrict__ P, float* Pmax, int do_max)
{
    if (P[30] != 0.f) return;
    __shared__ __attribute__((aligned(16))) float sh[56][72];
    __shared__ float su[36][72];
    __shared__ float ut[34][72];
    __shared__ float red[4];
    float (*pt)[72] = sh;

    const int tid = threadIdx.x;
    const int x0 = blockIdx.x * TX;
    const int y0 = blockIdx.y * TY;
    const int b  = blockIdx.z;
    const float* sb = src + (b << 18);
    const float* ib = img + (b << 18);
    const float* lb = lfd + (b << 18);
    float* db = dst + (b << 18);

    float kw[KS];
#pragma unroll
    for (int j = 0; j < KS; ++j) kw[j] = P[8 + j];
    const float alpha = P[0], lam = P[1], beta = P[2], xi = P[3];
    const float eta = P[4], nu = P[5], gam = P[6], omg = P[7];

#pragma unroll
    for (int p = 0; p < 9; ++p) {
        int i = tid + p * 256;
        if (i < 34 * 66) {
            int r = i / 66, c = i - r * 66;
            ut[r][c] = sb[refl(y0 - 1 + r, HH) * WW + refl(x0 - 1 + c, WW)];
        }
    }
#pragma unroll
    for (int p = 0; p < 4; ++p) {
        int i = tid + p * 256;
        if (i < 56 * 17) {
            int hr = i / 17, g = i - hr * 17;
            const float* row = sb + refl(y0 - 12 + hr, HH) * WW;
            int gxs = x0 - 12 + 4 * g;
            float wv[24];
            if (gxs >= 0 && gxs + 23 < WW) {
                const float4* p4 = (const float4*)(row + gxs);
#pragma unroll
                for (int q = 0; q < 6; ++q) {
                    float4 v = p4[q];
                    wv[4*q] = v.x; wv[4*q+1] = v.y; wv[4*q+2] = v.z; wv[4*q+3] = v.w;
                }
            } else {
#pragma unroll
                for (int q = 0; q < 24; ++q) wv[q] = row[refl(gxs + q, WW)];
            }
            float a0 = 0.f, a1 = 0.f, a2 = 0.f, a3 = 0.f;
#pragma unroll
            for (int j = 0; j < KS; ++j) {
                a0 = fmaf(kw[j], wv[j],     a0);
                a1 = fmaf(kw[j], wv[j + 1], a1);
                a2 = fmaf(kw[j], wv[j + 2], a2);
                a3 = fmaf(kw[j], wv[j + 3], a3);
            }
            float4 o; o.x = a0; o.y = a1; o.z = a2; o.w = a3;
            *(float4*)&sh[hr][4 * g] = o;
        }
    }
    __syncthreads();
#pragma unroll
    for (int p = 0; p < 3; ++p) {
        int i = tid + p * 256;
        if (i < 9 * 68) {
            int rg = i / 68, c = i - rg * 68;
            int r0 = rg * 4;
            float a0 = 0.f, a1 = 0.f, a2 = 0.f, a3 = 0.f;
#pragma unroll
            for (int q = 0; q < 24; ++q) {
                float s = sh[r0 + q][c];
                if (q <= 20)           a0 = fmaf(kw[q],     s, a0);
                if (q >= 1 && q <= 21) a1 = fmaf(kw[q - 1], s, a1);
                if (q >= 2 && q <= 22) a2 = fmaf(kw[q - 2], s, a2);
                if (q >= 3)            a3 = fmaf(kw[q - 3], s, a3);
            }
            su[r0][c] = a0; su[r0+1][c] = a1; su[r0+2][c] = a2; su[r0+3][c] = a3;
        }
    }
    __syncthreads();
#pragma unroll
    for (int p = 0; p < 9; ++p) {
        int i = tid + p * 256;
        if (i < 34 * 66) {
            int r = i / 66, c = i - r * 66;
            float gys = (su[r + 2][c + 1] - su[r][c + 1]) * 0.5f;
            float gxs = (su[r + 1][c + 2] - su[r + 1][c]) * 0.5f;
            float g2 = fmaf(gxs, gxs, fmaf(gys, gys, 1e-8f));
            float ph = fminf(beta * sqrtf(xi / fmaf(eta, g2, 1e-6f)), 10.f);
            float lv = lb[refl(y0 - 1 + r, HH) * WW + refl(x0 - 1 + c, WW)];
            float fwv = fminf(fmaxf(1.f - omg * lv, 0.f), 1.f);
            pt[r][c] = ph * fwv;
        }
    }
    __syncthreads();
    const int c = tid & 63, r0 = tid >> 6;
    float mymax = 0.f;
#pragma unroll
    for (int p = 0; p < 8; ++p) {
        int r = r0 + p * 4;
        float uc = ut[r + 1][c + 1];
        float uN = ut[r][c + 1],     uS = ut[r + 2][c + 1];
        float uE = ut[r + 1][c + 2], uW = ut[r + 1][c];
        float gy = (uS - uN) * 0.5f, gx = (uE - uW) * 0.5f;
        float lap = uN + uS + uE + uW - 4.f * uc;
        float gm = sqrtf(fmaf(gx, gx, fmaf(gy, gy, 1e-8f)));
        float s = gm * fabsf(lap);
        float psi = 1e-4f * sqrtf(fmaf(nu, s * s * s, gam));
        float pN = pt[r][c + 1],     pS = pt[r + 2][c + 1];
        float pE = pt[r + 1][c + 2], pW = pt[r + 1][c];
        float dv = pN * (uN - uc) + pS * (uS - uc) + pE * (uE - uc) + pW * (uW - uc);
        int gidx = (y0 + r) * WW + x0 + c;
        float u0v = ib[gidx];
        float du = alpha * psi * dv - lam * (uc - u0v);
        float un = fminf(fmaxf(fmaf(0.1f, du, uc), 0.f), 1.f);
        db[gidx] = un;
        if (do_max){
            float v = fabsf(u0v - un);
            resid[(b<<18) + gidx] = v;
            mymax = fmaxf(mymax, v);
        }
    }
    if (do_max) {
#pragma unroll
        for (int off = 32; off; off >>= 1) mymax = fmaxf(mymax, __shfl_down(mymax, off));
        if ((tid & 63) == 0) red[tid >> 6] = mymax;
        __syncthreads();
        if (tid == 0) {
            float m = fmaxf(fmaxf(red[0], red[1]), fmaxf(red[2], red[3]));
            atomicMax((unsigned int*)(Pmax + 32 * b), __float_as_uint(m));
        }
    }
}

// in-place normalize of residual
__global__ void k_res2(float* __restrict__ r, const float* __restrict__ Pmax)
{
    int i = blockIdx.x * 256 + threadIdx.x;   // float4 index
    int b = i >> 16;
    float inv = 1.f / (Pmax[32 * b] + 1e-8f);
    float4 v = ((const float4*)r)[i];
    v.x *= inv; v.y *= inv; v.z *= inv; v.w *= inv;
    ((float4*)r)[i] = v;
}

extern "C" void kernel_launch(void* const* d_in, const int* in_sizes, int n_in,
                              void* d_out, int out_size, void* d_ws, size_t ws_size,
                              hipStream_t stream)
{
    const float* image = (const float*)d_in[0];
    const float* lfd   = (const float*)d_in[1];

    float* out_u = (float*)d_out;
    float* out_r = out_u + NPIX;

    float* uB = (float*)d_ws;           // NPIX floats (fallback ping-pong)
    float* P  = uB + NPIX;              // params + max slots

    k_params<<<1, 64, 0, stream>>>((const float*)d_in[2], (const float*)d_in[3],
                                   (const float*)d_in[4], (const float*)d_in[5],
                                   (const float*)d_in[6], (const float*)d_in[7],
                                   (const float*)d_in[8], (const float*)d_in[9],
                                   (const float*)d_in[10], P);

    float* Pmax = P + 64;

    // saturated-phi fast path (no-op if not saturated)
    dim3 grd(WW/TX, HH/TY, 16), blk(256);
    k_mega<<<grd, blk, 0, stream>>>(image, lfd, out_u, out_r, P, Pmax);

    // general fallback (no-op if saturated)
    float* bufs[2] = { out_u, uB };
    for (int it = 0; it < 5; ++it) {
        const float* src = (it == 0) ? image : bufs[(it + 1) & 1];
        float* dstp = bufs[it & 1];
        k_iter<<<grd, blk, 0, stream>>>(src, image, lfd, dstp, out_r, P, Pmax, it == 4 ? 1 : 0);
    }

    k_res2<<<NPIX/1024, 256, 0, stream>>>(out_r, Pmax);
}